// Round 5
// baseline (500.450 us; speedup 1.0000x reference)
//
#include <hip/hip_runtime.h>

#define LLEN 131072
#define CDIM 64
#define NB 4
#define TP 62            // output positions per 64-wide window (1 halo each side)
#define NCH_A 5
#define BLKA 423         // 423*5 = 2115 windows, 2115*62 = 131130 >= 131072
#define NCH_C 5
#define BLKC 423
#define XSP 66           // xs pitch (floats): even -> float2 reads 8B-aligned
#define QHP 72           // qh/kh/vh pitch (halves): rows 144B (16B aligned)

typedef _Float16 half8 __attribute__((ext_vector_type(8)));
typedef _Float16 half4 __attribute__((ext_vector_type(4)));
typedef float f32x4 __attribute__((ext_vector_type(4)));
#define MFMA16 __builtin_amdgcn_mfma_f32_16x16x32_f16

// ---- cross-lane helpers (16-lane groups) ----
__device__ __forceinline__ float dpp_shr1(float v) {  // dst[c] = src[c-1], c==0 -> 0
  return __int_as_float(__builtin_amdgcn_update_dpp(
      0, __float_as_int(v), 0x111, 0xF, 0xF, true));
}
__device__ __forceinline__ float dpp_shl1(float v) {  // dst[c] = src[c+1], c==15 -> 0
  return __int_as_float(__builtin_amdgcn_update_dpp(
      0, __float_as_int(v), 0x101, 0xF, 0xF, true));
}
template <int PAT>
__device__ __forceinline__ float swz(float v) {       // pattern must be constexpr
  return __int_as_float(__builtin_amdgcn_ds_swizzle(__float_as_int(v), PAT));
}
#define SWZ_BC15 0x1F0   // every lane <- lane of its 16-group with c==15
#define SWZ_BC0  0x010   // every lane <- lane of its 16-group with c==0

// depthwise k=3 conv across positions, on 4 D-frags (pos = n*16+c), in place.
__device__ __forceinline__ void conv3(f32x4 a[4], const float* dwt, int c) {
  f32x4 o[4];
#pragma unroll
  for (int n = 0; n < 4; ++n) {
#pragma unroll
    for (int r = 0; r < 4; ++r) {
      const float cur = a[n][r];
      float lf = dpp_shr1(cur);
      const float lb = (n > 0) ? swz<SWZ_BC15>(a[n - 1][r]) : 0.f;
      lf = (c == 0) ? lb : lf;
      float rt = dpp_shl1(cur);
      const float rb = (n < 3) ? swz<SWZ_BC0>(a[n + 1][r]) : 0.f;
      rt = (c == 15) ? rb : rt;
      o[n][r] = dwt[0 * 4 + r] * lf + dwt[1 * 4 + r] * cur + dwt[2 * 4 + r] * rt;
    }
  }
#pragma unroll
  for (int n = 0; n < 4; ++n) a[n] = o[n];
}

// async-stage one 64ch x 64pos f32 x-tile into LDS xs[ci][pos] (pitch XSP)
__device__ __forceinline__ void stage_x(const float* __restrict__ xb,
                                        float* xs, int wv, int lane, int w0) {
  const int p = w0 - 1 + lane;
  const int pc = min(max(p, 0), LLEN - 1);
  const float* g0 = xb + pc;
#pragma unroll
  for (int k = 0; k < 16; ++k) {
    const int r = wv * 16 + k;
    __builtin_amdgcn_global_load_lds(
        (const __attribute__((address_space(1))) void*)(g0 + (size_t)r * LLEN),
        (__attribute__((address_space(3))) void*)(xs + r * XSP), 4, 0, 0);
  }
}

// Cooperative xs(f32) -> B-frag f16 table xf[frag][lane][8].
// frag f = ks*4+n; lane l: halves j = x[ci = ks*32+(l>>4)*8+j][pos = n*16+(l&15)].
// Thread t handles frag f = t>>5, lanes l0 = (t&31)*2 and l0+1 (pos, pos+1).
// Out-of-sequence positions are zeroed here (replaces post-GEMM pad masking).
__device__ __forceinline__ void convert_xf(const float* __restrict__ xs,
                                           _Float16* __restrict__ xf,
                                           int tid, int w0) {
  const int f   = tid >> 5;
  const int l0  = (tid & 31) * 2;
  const int ks  = f >> 2, n = f & 3;
  const int ci0 = ks * 32 + (l0 >> 4) * 8;
  const int pos = n * 16 + (l0 & 15);
  const int P0  = w0 - 1 + pos;
  const bool v0 = (P0 >= 0) && (P0 < LLEN);
  const bool v1 = (P0 + 1 >= 0) && (P0 + 1 < LLEN);
  half8 h0, h1;
#pragma unroll
  for (int j = 0; j < 8; ++j) {
    const float2 s = *(const float2*)&xs[(ci0 + j) * XSP + pos];
    h0[j] = (_Float16)(v0 ? s.x : 0.f);
    h1[j] = (_Float16)(v1 ? s.y : 0.f);
  }
  *(half8*)(xf + (f * 64 + l0) * 8) = h0;
  *(half8*)(xf + (f * 64 + l0 + 1) * 8) = h1;
}

// ---------------- prep: f16 A-fragment weight tables --------------------------
__global__ void prep_kernel(const float* __restrict__ w_q,
                            const float* __restrict__ w_kv,
                            _Float16* __restrict__ wqA, _Float16* __restrict__ wkA,
                            _Float16* __restrict__ wvA) {
  const int t = blockIdx.x * 256 + threadIdx.x;  // 0..4095
  const int j = t & 7;
  const int row = t >> 3;          // 0..511
  const int lane = row & 63;
  const int frag = row >> 6;       // m*2+ks
  const int m = frag >> 1, ks = frag & 1;
  const int ch = m * 16 + (lane & 15);
  const int ci = ks * 32 + ((lane >> 4) & 3) * 8 + j;
  wqA[t] = (_Float16)w_q[ch * 64 + ci];
  wkA[t] = (_Float16)w_kv[ch * 64 + ci];
  wvA[t] = (_Float16)w_kv[(64 + ch) * 64 + ci];
}

// ---------------- Kernel A: coop cvt -> MFMA q/k GEMM -> conv -> MFMA Gram ---
__global__ __launch_bounds__(256, 4) void qk_gram_kernel(
    const float* __restrict__ x, const _Float16* __restrict__ wqA,
    const _Float16* __restrict__ wkA, const float* __restrict__ w_q_dw,
    const float* __restrict__ w_kv_dw, float* __restrict__ G,
    float* __restrict__ nq, float* __restrict__ nk) {
  __shared__ __attribute__((aligned(16))) float xs[64 * XSP];       // 16.9 KB
  __shared__ __attribute__((aligned(16))) _Float16 qh[64 * QHP];    // 9.2 KB
  __shared__ __attribute__((aligned(16))) _Float16 ku[64 * QHP];    // 9.2 KB: xf / kh

  const int tid  = threadIdx.x;
  const int lane = tid & 63;
  const int wv   = __builtin_amdgcn_readfirstlane(tid >> 6);
  const int g    = lane >> 4;       // 0..3
  const int c    = lane & 15;       // 0..15
  const int b    = blockIdx.y;

  const float* xb = x + (size_t)b * CDIM * LLEN;

  half8 aQ[2], aK[2];
#pragma unroll
  for (int ks = 0; ks < 2; ++ks) {
    aQ[ks] = *(const half8*)(wqA + ((wv * 2 + ks) * 64 + lane) * 8);
    aK[ks] = *(const half8*)(wkA + ((wv * 2 + ks) * 64 + lane) * 8);
  }
  float dwq[12], dwk[12];
#pragma unroll
  for (int r = 0; r < 4; ++r) {
    const int ch = wv * 16 + g * 4 + r;
#pragma unroll
    for (int t = 0; t < 3; ++t) {
      dwq[t * 4 + r] = w_q_dw[ch * 3 + t];
      dwk[t * 4 + r] = w_kv_dw[ch * 3 + t];   // k = rows 0..63 of w_kv_dw
    }
  }

  f32x4 gacc[4];          // Gram: rows m*16+g*4+r, col wv*16+c (accum all windows)
#pragma unroll
  for (int m = 0; m < 4; ++m)
#pragma unroll
    for (int r = 0; r < 4; ++r) gacc[m][r] = 0.f;
  float nrmq[4] = {0.f, 0.f, 0.f, 0.f}, nrmk[4] = {0.f, 0.f, 0.f, 0.f};

  stage_x(xb, xs, wv, lane, blockIdx.x * NCH_A * TP);
  __syncthreads();   // xs(0) ready

  for (int ck = 0; ck < NCH_A; ++ck) {
    const int w0 = (blockIdx.x * NCH_A + ck) * TP;

    // 1. cooperative f32->f16 conversion into B-frag table (in ku)
    convert_xf(xs, ku, tid, w0);
    __syncthreads();   // B1: xf ready; xs reads done

    // prefetch next window's x; covered by GEMM+conv below
    if (ck + 1 < NCH_A)
      stage_x(xb, xs, wv, lane, (blockIdx.x * NCH_A + ck + 1) * TP);

    // 2. q/k GEMM straight from frag table (8 x ds_read_b128)
    f32x4 qacc[4], kacc[4];
#pragma unroll
    for (int n = 0; n < 4; ++n)
#pragma unroll
      for (int r = 0; r < 4; ++r) { qacc[n][r] = 0.f; kacc[n][r] = 0.f; }
#pragma unroll
    for (int ks = 0; ks < 2; ++ks) {
#pragma unroll
      for (int n = 0; n < 4; ++n) {
        const half8 bf = *(const half8*)(ku + ((ks * 4 + n) * 64 + lane) * 8);
        qacc[n] = MFMA16(aQ[ks], bf, qacc[n], 0, 0, 0);
        kacc[n] = MFMA16(aK[ks], bf, kacc[n], 0, 0, 0);
      }
    }
    conv3(qacc, dwq, c);
    conv3(kacc, dwk, c);
    __syncthreads();   // B2: all xf reads done (ku free for kh)

    // 3. round to f16 (norms from the SAME rounded values), store q->qh, k->ku
#pragma unroll
    for (int n = 0; n < 4; ++n) {
      const int pos = n * 16 + c;
      const bool ok = (pos >= 1) && (pos <= 62) && (w0 - 1 + pos < LLEN);
#pragma unroll
      for (int r = 0; r < 4; ++r) {
        const _Float16 hq = ok ? (_Float16)qacc[n][r] : (_Float16)0.f;
        const _Float16 hk = ok ? (_Float16)kacc[n][r] : (_Float16)0.f;
        const float fq = (float)hq, fk = (float)hk;
        nrmq[r] = fmaf(fq, fq, nrmq[r]);
        nrmk[r] = fmaf(fk, fk, nrmk[r]);
        qh[(wv * 16 + g * 4 + r) * QHP + pos] = hq;
        ku[(wv * 16 + g * 4 + r) * QHP + pos] = hk;
      }
    }
    __syncthreads();   // B3: qh/kh visible

    // 4. Gram: G += Q * K^T over this window's 64 (zero-padded) positions
    {
      const _Float16* kcol = ku + (wv * 16 + c) * QHP + g * 8;
      const half8 bK0 = *(const half8*)(kcol);
      const half8 bK1 = *(const half8*)(kcol + 32);
#pragma unroll
      for (int m = 0; m < 4; ++m) {
        const _Float16* qrow = qh + (m * 16 + c) * QHP + g * 8;
        const half8 a0 = *(const half8*)(qrow);
        const half8 a1 = *(const half8*)(qrow + 32);
        gacc[m] = MFMA16(a0, bK0, gacc[m], 0, 0, 0);
        gacc[m] = MFMA16(a1, bK1, gacc[m], 0, 0, 0);
      }
    }
    __syncthreads();   // B4: Gram reads done; drains stage vmcnt
  }

  // ---- finalize: G atomics, norm reduce+atomics
  float* Gb = G + b * 4096;
#pragma unroll
  for (int m = 0; m < 4; ++m)
#pragma unroll
    for (int r = 0; r < 4; ++r)
      atomicAdd(&Gb[(m * 16 + g * 4 + r) * 64 + wv * 16 + c], gacc[m][r]);

#pragma unroll
  for (int r = 0; r < 4; ++r) {
    nrmq[r] += __shfl_xor(nrmq[r], 1);  nrmk[r] += __shfl_xor(nrmk[r], 1);
    nrmq[r] += __shfl_xor(nrmq[r], 2);  nrmk[r] += __shfl_xor(nrmk[r], 2);
    nrmq[r] += __shfl_xor(nrmq[r], 4);  nrmk[r] += __shfl_xor(nrmk[r], 4);
    nrmq[r] += __shfl_xor(nrmq[r], 8);  nrmk[r] += __shfl_xor(nrmk[r], 8);
  }
  if (c == 0) {
#pragma unroll
    for (int r = 0; r < 4; ++r) {
      atomicAdd(&nq[b * 64 + wv * 16 + g * 4 + r], nrmq[r]);
      atomicAdd(&nk[b * 64 + wv * 16 + g * 4 + r], nrmk[r]);
    }
  }
}

// ---------------- Kernel B: softmax -> M = w_proj@attn -> f16 A-frag table ---
__global__ void attn_proj_kernel(const float* __restrict__ G,
                                 const float* __restrict__ nq,
                                 const float* __restrict__ nk,
                                 const float* __restrict__ w_proj,
                                 const float* __restrict__ temperature,
                                 _Float16* __restrict__ Mh) {
  __shared__ float attn_s[64][65];
  __shared__ float Ms[64][65];
  __shared__ float invq_s[64];
  __shared__ float invk_s[64];
  const int b = blockIdx.x;
  const int tid = threadIdx.x;
  if (tid < 64)       invq_s[tid]      = 1.f / fmaxf(sqrtf(nq[b * 64 + tid]), 1e-12f);
  else if (tid < 128) invk_s[tid - 64] = 1.f / fmaxf(sqrtf(nk[b * 64 + tid - 64]), 1e-12f);
  __syncthreads();
  const float temp = temperature[b];
  if (tid < 64) {
    const int cq = tid;
    const float* Gr = G + b * 4096 + cq * 64;
    const float iq = invq_s[cq] * temp;
    float z[64];
    float m = -1e30f;
#pragma unroll
    for (int d = 0; d < 64; ++d) { z[d] = Gr[d] * iq * invk_s[d]; m = fmaxf(m, z[d]); }
    float s = 0.f;
#pragma unroll
    for (int d = 0; d < 64; ++d) { z[d] = expf(z[d] - m); s += z[d]; }
    const float inv = 1.f / s;
#pragma unroll
    for (int d = 0; d < 64; ++d) attn_s[cq][d] = z[d] * inv;
  }
  __syncthreads();
  const int o = tid & 63;
  const int dg = tid >> 6;
  for (int d = dg * 16; d < dg * 16 + 16; ++d) {
    float s = 0.f;
#pragma unroll
    for (int cc = 0; cc < 64; ++cc) s = fmaf(w_proj[o * 64 + cc], attn_s[cc][d], s);
    Ms[o][d] = s;
  }
  __syncthreads();
  for (int e = tid; e < 512; e += 256) {
    const int lane_ = e & 63, frag = e >> 6;
    const int m = frag >> 1, ks = frag & 1;
    const int o_ = m * 16 + (lane_ & 15);
    const int d0 = ks * 32 + ((lane_ >> 4) & 3) * 8;
    _Float16* dst = Mh + b * 4096 + e * 8;
#pragma unroll
    for (int j = 0; j < 8; ++j) dst[j] = (_Float16)Ms[o_][d0 + j];
  }
}

// ---------------- Kernel C: coop cvt -> MFMA v GEMM -> conv -> out = M@V -----
__global__ __launch_bounds__(256, 5) void out_kernel(
    const float* __restrict__ x, const _Float16* __restrict__ wvA,
    const float* __restrict__ w_kv_dw, const _Float16* __restrict__ Mh,
    float* __restrict__ out) {
  __shared__ __attribute__((aligned(16))) float xs[64 * XSP];     // 16.9 KB
  __shared__ __attribute__((aligned(16))) _Float16 vu[64 * QHP];  // 9.2 KB: xf / vh

  const int tid  = threadIdx.x;
  const int lane = tid & 63;
  const int wv   = __builtin_amdgcn_readfirstlane(tid >> 6);
  const int g    = lane >> 4;
  const int c    = lane & 15;
  const int b    = blockIdx.y;

  const float* xb = x + (size_t)b * CDIM * LLEN;
  float* ob = out + (size_t)b * CDIM * LLEN;

  half8 aV[2], aM[2];
#pragma unroll
  for (int ks = 0; ks < 2; ++ks) {
    aV[ks] = *(const half8*)(wvA + ((wv * 2 + ks) * 64 + lane) * 8);
    aM[ks] = *(const half8*)(Mh + b * 4096 + ((wv * 2 + ks) * 64 + lane) * 8);
  }
  float dwv[12];
#pragma unroll
  for (int r = 0; r < 4; ++r) {
    const int ch = wv * 16 + g * 4 + r;
#pragma unroll
    for (int t = 0; t < 3; ++t) dwv[t * 4 + r] = w_kv_dw[(64 + ch) * 3 + t];
  }

  stage_x(xb, xs, wv, lane, blockIdx.x * NCH_C * TP);
  __syncthreads();

  for (int ck = 0; ck < NCH_C; ++ck) {
    const int w0 = (blockIdx.x * NCH_C + ck) * TP;

    // 1. cooperative conversion into B-frag table (in vu)
    convert_xf(xs, vu, tid, w0);
    __syncthreads();   // B1: xf ready; xs free

    if (ck + 1 < NCH_C)
      stage_x(xb, xs, wv, lane, (blockIdx.x * NCH_C + ck + 1) * TP);

    // 2. v GEMM from frag table
    f32x4 vacc[4];
#pragma unroll
    for (int n = 0; n < 4; ++n)
#pragma unroll
      for (int r = 0; r < 4; ++r) vacc[n][r] = 0.f;
#pragma unroll
    for (int ks = 0; ks < 2; ++ks) {
#pragma unroll
      for (int n = 0; n < 4; ++n) {
        const half8 bf = *(const half8*)(vu + ((ks * 4 + n) * 64 + lane) * 8);
        vacc[n] = MFMA16(aV[ks], bf, vacc[n], 0, 0, 0);
      }
    }
    conv3(vacc, dwv, c);
    __syncthreads();   // B2: xf reads done (vu free for vh)

    // 3. round + store vh[pos][d] as f16x4 b64 (conflict-light)
#pragma unroll
    for (int n = 0; n < 4; ++n) {
      const int pos = n * 16 + c;
      const bool ok = (pos >= 1) && (pos <= 62) && (w0 - 1 + pos < LLEN);
      half4 hv;
#pragma unroll
      for (int r = 0; r < 4; ++r)
        hv[r] = ok ? (_Float16)vacc[n][r] : (_Float16)0.f;
      *(half4*)(vu + pos * QHP + wv * 16 + g * 4) = hv;
    }
    __syncthreads();   // B3: vh visible

    // 4. out GEMM: rows o (wv quarter), cols pos, contract d
    f32x4 oacc[4];
#pragma unroll
    for (int n = 0; n < 4; ++n)
#pragma unroll
      for (int r = 0; r < 4; ++r) oacc[n][r] = 0.f;
#pragma unroll
    for (int n = 0; n < 4; ++n) {
      const _Float16* vrow = vu + (n * 16 + c) * QHP + g * 8;
      const half8 b0 = *(const half8*)(vrow);
      const half8 b1 = *(const half8*)(vrow + 32);
      oacc[n] = MFMA16(aM[0], b0, oacc[n], 0, 0, 0);
      oacc[n] = MFMA16(aM[1], b1, oacc[n], 0, 0, 0);
    }
#pragma unroll
    for (int n = 0; n < 4; ++n) {
      const int pos = n * 16 + c;
      const int P = w0 - 1 + pos;
      if (pos >= 1 && pos <= 62 && P < LLEN) {
#pragma unroll
        for (int r = 0; r < 4; ++r)
          ob[(size_t)(wv * 16 + g * 4 + r) * LLEN + P] = oacc[n][r];
      }
    }
    __syncthreads();   // B4: vh reads done; drains stage vmcnt
  }
}

extern "C" void kernel_launch(void* const* d_in, const int* in_sizes, int n_in,
                              void* d_out, int out_size, void* d_ws, size_t ws_size,
                              hipStream_t stream) {
  (void)in_sizes; (void)n_in; (void)out_size; (void)ws_size;
  const float* x           = (const float*)d_in[0];
  const float* w_kv        = (const float*)d_in[1];
  const float* w_kv_dw     = (const float*)d_in[2];
  const float* w_q         = (const float*)d_in[3];
  const float* w_q_dw      = (const float*)d_in[4];
  const float* w_proj      = (const float*)d_in[5];
  const float* temperature = (const float*)d_in[6];
  float* out = (float*)d_out;

  float* G   = (float*)d_ws;            // 16384 f32
  float* nqp = G + 16384;               // 256
  float* nkp = nqp + 256;               // 256
  _Float16* Mh  = (_Float16*)(nkp + 256);  // 4*4096 halves
  _Float16* wqA = Mh + NB * 4096;       // 4096 halves each
  _Float16* wkA = wqA + 4096;
  _Float16* wvA = wkA + 4096;

  (void)hipMemsetAsync(G, 0, (size_t)(16384 + 512) * sizeof(float), stream);
  prep_kernel<<<dim3(16), dim3(256), 0, stream>>>(w_q, w_kv, wqA, wkA, wvA);
  qk_gram_kernel<<<dim3(BLKA, NB), dim3(256), 0, stream>>>(
      x, wqA, wkA, w_q_dw, w_kv_dw, G, nqp, nkp);
  attn_proj_kernel<<<dim3(NB), dim3(256), 0, stream>>>(
      G, nqp, nkp, w_proj, temperature, Mh);
  out_kernel<<<dim3(BLKC, NB), dim3(256), 0, stream>>>(
      x, wvA, w_kv_dw, Mh, out);
}

// Round 6
// 422.927 us; speedup vs baseline: 1.1833x; 1.1833x over previous
//
#include <hip/hip_runtime.h>

#define LLEN 131072
#define CDIM 64
#define NB 4
#define TP 62            // output positions per 64-wide window (1 halo each side)
#define NCH_A 5
#define BLKA 423         // 423*5 = 2115 windows, 2115*62 = 131130 >= 131072
#define NCH_C 5
#define BLKC 423
#define XSP 66           // xs pitch (floats): even -> float2 reads 8B-aligned
#define QHP 72           // qh/kh/vh pitch (halves): rows 144B (16B aligned)

typedef _Float16 half8 __attribute__((ext_vector_type(8)));
typedef _Float16 half4 __attribute__((ext_vector_type(4)));
typedef float f32x4 __attribute__((ext_vector_type(4)));
#define MFMA16 __builtin_amdgcn_mfma_f32_16x16x32_f16

// ---- cross-lane helpers (16-lane groups) ----
__device__ __forceinline__ float dpp_shr1(float v) {  // dst[c] = src[c-1], c==0 -> 0
  return __int_as_float(__builtin_amdgcn_update_dpp(
      0, __float_as_int(v), 0x111, 0xF, 0xF, true));
}
__device__ __forceinline__ float dpp_shl1(float v) {  // dst[c] = src[c+1], c==15 -> 0
  return __int_as_float(__builtin_amdgcn_update_dpp(
      0, __float_as_int(v), 0x101, 0xF, 0xF, true));
}
template <int PAT>
__device__ __forceinline__ float swz(float v) {       // pattern must be constexpr
  return __int_as_float(__builtin_amdgcn_ds_swizzle(__float_as_int(v), PAT));
}
#define SWZ_BC15 0x1F0   // every lane <- lane of its 16-group with c==15
#define SWZ_BC0  0x010   // every lane <- lane of its 16-group with c==0

// depthwise k=3 conv across positions, on 4 D-frags (pos = n*16+c), in place.
__device__ __forceinline__ void conv3(f32x4 a[4], const float* dwt, int c) {
  f32x4 o[4];
#pragma unroll
  for (int n = 0; n < 4; ++n) {
#pragma unroll
    for (int r = 0; r < 4; ++r) {
      const float cur = a[n][r];
      float lf = dpp_shr1(cur);
      const float lb = (n > 0) ? swz<SWZ_BC15>(a[n - 1][r]) : 0.f;
      lf = (c == 0) ? lb : lf;
      float rt = dpp_shl1(cur);
      const float rb = (n < 3) ? swz<SWZ_BC0>(a[n + 1][r]) : 0.f;
      rt = (c == 15) ? rb : rt;
      o[n][r] = dwt[0 * 4 + r] * lf + dwt[1 * 4 + r] * cur + dwt[2 * 4 + r] * rt;
    }
  }
#pragma unroll
  for (int n = 0; n < 4; ++n) a[n] = o[n];
}

// async-stage one 64ch x 64pos f32 x-tile into LDS xs[ci][pos] (pitch XSP)
__device__ __forceinline__ void stage_x(const float* __restrict__ xb,
                                        float* xs, int wv, int lane, int w0) {
  const int p = w0 - 1 + lane;
  const int pc = min(max(p, 0), LLEN - 1);
  const float* g0 = xb + pc;
#pragma unroll
  for (int k = 0; k < 16; ++k) {
    const int r = wv * 16 + k;
    __builtin_amdgcn_global_load_lds(
        (const __attribute__((address_space(1))) void*)(g0 + (size_t)r * LLEN),
        (__attribute__((address_space(3))) void*)(xs + r * XSP), 4, 0, 0);
  }
}

// Cooperative xs(f32) -> B-frag f16 table xf[frag][lane][8].
// frag f = ks*4+n; lane l: halves j = x[ci = ks*32+(l>>4)*8+j][pos = n*16+(l&15)].
// Thread t handles frag f = t>>5, lanes l0 = (t&31)*2 and l0+1 (pos, pos+1).
// Out-of-sequence positions are zeroed here (replaces post-GEMM pad masking).
__device__ __forceinline__ void convert_xf(const float* __restrict__ xs,
                                           _Float16* __restrict__ xf,
                                           int tid, int w0) {
  const int f   = tid >> 5;
  const int l0  = (tid & 31) * 2;
  const int ks  = f >> 2, n = f & 3;
  const int ci0 = ks * 32 + (l0 >> 4) * 8;
  const int pos = n * 16 + (l0 & 15);
  const int P0  = w0 - 1 + pos;
  const bool v0 = (P0 >= 0) && (P0 < LLEN);
  const bool v1 = (P0 + 1 >= 0) && (P0 + 1 < LLEN);
  half8 h0, h1;
#pragma unroll
  for (int j = 0; j < 8; ++j) {
    const float2 s = *(const float2*)&xs[(ci0 + j) * XSP + pos];
    h0[j] = (_Float16)(v0 ? s.x : 0.f);
    h1[j] = (_Float16)(v1 ? s.y : 0.f);
  }
  *(half8*)(xf + (f * 64 + l0) * 8) = h0;
  *(half8*)(xf + (f * 64 + l0 + 1) * 8) = h1;
}

// ---------------- prep: f16 A-fragment weight tables --------------------------
__global__ void prep_kernel(const float* __restrict__ w_q,
                            const float* __restrict__ w_kv,
                            _Float16* __restrict__ wqA, _Float16* __restrict__ wkA,
                            _Float16* __restrict__ wvA) {
  const int t = blockIdx.x * 256 + threadIdx.x;  // 0..4095
  const int j = t & 7;
  const int row = t >> 3;          // 0..511
  const int lane = row & 63;
  const int frag = row >> 6;       // m*2+ks
  const int m = frag >> 1, ks = frag & 1;
  const int ch = m * 16 + (lane & 15);
  const int ci = ks * 32 + ((lane >> 4) & 3) * 8 + j;
  wqA[t] = (_Float16)w_q[ch * 64 + ci];
  wkA[t] = (_Float16)w_kv[ch * 64 + ci];
  wvA[t] = (_Float16)w_kv[(64 + ch) * 64 + ci];
}

// ---------------- Kernel A: coop cvt -> MFMA q/k GEMM -> conv -> MFMA Gram ---
// NOTE: plain launch_bounds — (256,4) clamps VGPR to 64 and spills the MFMA
// accumulators (r5: +315 MB scratch traffic). Natural allocation is ~92 VGPR.
__global__ __launch_bounds__(256) void qk_gram_kernel(
    const float* __restrict__ x, const _Float16* __restrict__ wqA,
    const _Float16* __restrict__ wkA, const float* __restrict__ w_q_dw,
    const float* __restrict__ w_kv_dw, float* __restrict__ G,
    float* __restrict__ nq, float* __restrict__ nk) {
  __shared__ __attribute__((aligned(16))) float xs[64 * XSP];       // 16.9 KB
  __shared__ __attribute__((aligned(16))) _Float16 qh[64 * QHP];    // 9.2 KB
  __shared__ __attribute__((aligned(16))) _Float16 ku[64 * QHP];    // 9.2 KB: xf / kh

  const int tid  = threadIdx.x;
  const int lane = tid & 63;
  const int wv   = __builtin_amdgcn_readfirstlane(tid >> 6);
  const int g    = lane >> 4;       // 0..3
  const int c    = lane & 15;       // 0..15
  const int b    = blockIdx.y;

  const float* xb = x + (size_t)b * CDIM * LLEN;

  half8 aQ[2], aK[2];
#pragma unroll
  for (int ks = 0; ks < 2; ++ks) {
    aQ[ks] = *(const half8*)(wqA + ((wv * 2 + ks) * 64 + lane) * 8);
    aK[ks] = *(const half8*)(wkA + ((wv * 2 + ks) * 64 + lane) * 8);
  }
  float dwq[12], dwk[12];
#pragma unroll
  for (int r = 0; r < 4; ++r) {
    const int ch = wv * 16 + g * 4 + r;
#pragma unroll
    for (int t = 0; t < 3; ++t) {
      dwq[t * 4 + r] = w_q_dw[ch * 3 + t];
      dwk[t * 4 + r] = w_kv_dw[ch * 3 + t];   // k = rows 0..63 of w_kv_dw
    }
  }

  f32x4 gacc[4];          // Gram: rows m*16+g*4+r, col wv*16+c (accum all windows)
#pragma unroll
  for (int m = 0; m < 4; ++m)
#pragma unroll
    for (int r = 0; r < 4; ++r) gacc[m][r] = 0.f;
  float nrmq[4] = {0.f, 0.f, 0.f, 0.f}, nrmk[4] = {0.f, 0.f, 0.f, 0.f};

  stage_x(xb, xs, wv, lane, blockIdx.x * NCH_A * TP);
  __syncthreads();   // xs(0) ready

  for (int ck = 0; ck < NCH_A; ++ck) {
    const int w0 = (blockIdx.x * NCH_A + ck) * TP;

    // 1. cooperative f32->f16 conversion into B-frag table (in ku)
    convert_xf(xs, ku, tid, w0);
    __syncthreads();   // B1: xf ready; xs reads done

    // prefetch next window's x; covered by GEMM+conv below
    if (ck + 1 < NCH_A)
      stage_x(xb, xs, wv, lane, (blockIdx.x * NCH_A + ck + 1) * TP);

    // 2. q/k GEMM straight from frag table (8 x ds_read_b128)
    f32x4 qacc[4], kacc[4];
#pragma unroll
    for (int n = 0; n < 4; ++n)
#pragma unroll
      for (int r = 0; r < 4; ++r) { qacc[n][r] = 0.f; kacc[n][r] = 0.f; }
#pragma unroll
    for (int ks = 0; ks < 2; ++ks) {
#pragma unroll
      for (int n = 0; n < 4; ++n) {
        const half8 bf = *(const half8*)(ku + ((ks * 4 + n) * 64 + lane) * 8);
        qacc[n] = MFMA16(aQ[ks], bf, qacc[n], 0, 0, 0);
        kacc[n] = MFMA16(aK[ks], bf, kacc[n], 0, 0, 0);
      }
    }
    conv3(qacc, dwq, c);
    conv3(kacc, dwk, c);
    __syncthreads();   // B2: all xf reads done (ku free for kh)

    // 3. round to f16 (norms from the SAME rounded values), store q->qh, k->ku
#pragma unroll
    for (int n = 0; n < 4; ++n) {
      const int pos = n * 16 + c;
      const bool ok = (pos >= 1) && (pos <= 62) && (w0 - 1 + pos < LLEN);
#pragma unroll
      for (int r = 0; r < 4; ++r) {
        const _Float16 hq = ok ? (_Float16)qacc[n][r] : (_Float16)0.f;
        const _Float16 hk = ok ? (_Float16)kacc[n][r] : (_Float16)0.f;
        const float fq = (float)hq, fk = (float)hk;
        nrmq[r] = fmaf(fq, fq, nrmq[r]);
        nrmk[r] = fmaf(fk, fk, nrmk[r]);
        qh[(wv * 16 + g * 4 + r) * QHP + pos] = hq;
        ku[(wv * 16 + g * 4 + r) * QHP + pos] = hk;
      }
    }
    __syncthreads();   // B3: qh/kh visible

    // 4. Gram: G += Q * K^T over this window's 64 (zero-padded) positions
    {
      const _Float16* kcol = ku + (wv * 16 + c) * QHP + g * 8;
      const half8 bK0 = *(const half8*)(kcol);
      const half8 bK1 = *(const half8*)(kcol + 32);
#pragma unroll
      for (int m = 0; m < 4; ++m) {
        const _Float16* qrow = qh + (m * 16 + c) * QHP + g * 8;
        const half8 a0 = *(const half8*)(qrow);
        const half8 a1 = *(const half8*)(qrow + 32);
        gacc[m] = MFMA16(a0, bK0, gacc[m], 0, 0, 0);
        gacc[m] = MFMA16(a1, bK1, gacc[m], 0, 0, 0);
      }
    }
    __syncthreads();   // B4: Gram reads done; drains stage vmcnt
  }

  // ---- finalize: G atomics, norm reduce+atomics
  float* Gb = G + b * 4096;
#pragma unroll
  for (int m = 0; m < 4; ++m)
#pragma unroll
    for (int r = 0; r < 4; ++r)
      atomicAdd(&Gb[(m * 16 + g * 4 + r) * 64 + wv * 16 + c], gacc[m][r]);

#pragma unroll
  for (int r = 0; r < 4; ++r) {
    nrmq[r] += __shfl_xor(nrmq[r], 1);  nrmk[r] += __shfl_xor(nrmk[r], 1);
    nrmq[r] += __shfl_xor(nrmq[r], 2);  nrmk[r] += __shfl_xor(nrmk[r], 2);
    nrmq[r] += __shfl_xor(nrmq[r], 4);  nrmk[r] += __shfl_xor(nrmk[r], 4);
    nrmq[r] += __shfl_xor(nrmq[r], 8);  nrmk[r] += __shfl_xor(nrmk[r], 8);
  }
  if (c == 0) {
#pragma unroll
    for (int r = 0; r < 4; ++r) {
      atomicAdd(&nq[b * 64 + wv * 16 + g * 4 + r], nrmq[r]);
      atomicAdd(&nk[b * 64 + wv * 16 + g * 4 + r], nrmk[r]);
    }
  }
}

// ---------------- Kernel B: softmax -> M = w_proj@attn -> f16 A-frag table ---
__global__ void attn_proj_kernel(const float* __restrict__ G,
                                 const float* __restrict__ nq,
                                 const float* __restrict__ nk,
                                 const float* __restrict__ w_proj,
                                 const float* __restrict__ temperature,
                                 _Float16* __restrict__ Mh) {
  __shared__ float attn_s[64][65];
  __shared__ float Ms[64][65];
  __shared__ float invq_s[64];
  __shared__ float invk_s[64];
  const int b = blockIdx.x;
  const int tid = threadIdx.x;
  if (tid < 64)       invq_s[tid]      = 1.f / fmaxf(sqrtf(nq[b * 64 + tid]), 1e-12f);
  else if (tid < 128) invk_s[tid - 64] = 1.f / fmaxf(sqrtf(nk[b * 64 + tid - 64]), 1e-12f);
  __syncthreads();
  const float temp = temperature[b];
  if (tid < 64) {
    const int cq = tid;
    const float* Gr = G + b * 4096 + cq * 64;
    const float iq = invq_s[cq] * temp;
    float z[64];
    float m = -1e30f;
#pragma unroll
    for (int d = 0; d < 64; ++d) { z[d] = Gr[d] * iq * invk_s[d]; m = fmaxf(m, z[d]); }
    float s = 0.f;
#pragma unroll
    for (int d = 0; d < 64; ++d) { z[d] = expf(z[d] - m); s += z[d]; }
    const float inv = 1.f / s;
#pragma unroll
    for (int d = 0; d < 64; ++d) attn_s[cq][d] = z[d] * inv;
  }
  __syncthreads();
  const int o = tid & 63;
  const int dg = tid >> 6;
  for (int d = dg * 16; d < dg * 16 + 16; ++d) {
    float s = 0.f;
#pragma unroll
    for (int cc = 0; cc < 64; ++cc) s = fmaf(w_proj[o * 64 + cc], attn_s[cc][d], s);
    Ms[o][d] = s;
  }
  __syncthreads();
  for (int e = tid; e < 512; e += 256) {
    const int lane_ = e & 63, frag = e >> 6;
    const int m = frag >> 1, ks = frag & 1;
    const int o_ = m * 16 + (lane_ & 15);
    const int d0 = ks * 32 + ((lane_ >> 4) & 3) * 8;
    _Float16* dst = Mh + b * 4096 + e * 8;
#pragma unroll
    for (int j = 0; j < 8; ++j) dst[j] = (_Float16)Ms[o_][d0 + j];
  }
}

// ---------------- Kernel C: coop cvt -> MFMA v GEMM -> conv -> out = M@V -----
__global__ __launch_bounds__(256) void out_kernel(
    const float* __restrict__ x, const _Float16* __restrict__ wvA,
    const float* __restrict__ w_kv_dw, const _Float16* __restrict__ Mh,
    float* __restrict__ out) {
  __shared__ __attribute__((aligned(16))) float xs[64 * XSP];     // 16.9 KB
  __shared__ __attribute__((aligned(16))) _Float16 vu[64 * QHP];  // 9.2 KB: xf / vh

  const int tid  = threadIdx.x;
  const int lane = tid & 63;
  const int wv   = __builtin_amdgcn_readfirstlane(tid >> 6);
  const int g    = lane >> 4;
  const int c    = lane & 15;
  const int b    = blockIdx.y;

  const float* xb = x + (size_t)b * CDIM * LLEN;
  float* ob = out + (size_t)b * CDIM * LLEN;

  half8 aV[2], aM[2];
#pragma unroll
  for (int ks = 0; ks < 2; ++ks) {
    aV[ks] = *(const half8*)(wvA + ((wv * 2 + ks) * 64 + lane) * 8);
    aM[ks] = *(const half8*)(Mh + b * 4096 + ((wv * 2 + ks) * 64 + lane) * 8);
  }
  float dwv[12];
#pragma unroll
  for (int r = 0; r < 4; ++r) {
    const int ch = wv * 16 + g * 4 + r;
#pragma unroll
    for (int t = 0; t < 3; ++t) dwv[t * 4 + r] = w_kv_dw[(64 + ch) * 3 + t];
  }

  stage_x(xb, xs, wv, lane, blockIdx.x * NCH_C * TP);
  __syncthreads();

  for (int ck = 0; ck < NCH_C; ++ck) {
    const int w0 = (blockIdx.x * NCH_C + ck) * TP;

    // 1. cooperative conversion into B-frag table (in vu)
    convert_xf(xs, vu, tid, w0);
    __syncthreads();   // B1: xf ready; xs free

    if (ck + 1 < NCH_C)
      stage_x(xb, xs, wv, lane, (blockIdx.x * NCH_C + ck + 1) * TP);

    // 2. v GEMM from frag table
    f32x4 vacc[4];
#pragma unroll
    for (int n = 0; n < 4; ++n)
#pragma unroll
      for (int r = 0; r < 4; ++r) vacc[n][r] = 0.f;
#pragma unroll
    for (int ks = 0; ks < 2; ++ks) {
#pragma unroll
      for (int n = 0; n < 4; ++n) {
        const half8 bf = *(const half8*)(vu + ((ks * 4 + n) * 64 + lane) * 8);
        vacc[n] = MFMA16(aV[ks], bf, vacc[n], 0, 0, 0);
      }
    }
    conv3(vacc, dwv, c);
    __syncthreads();   // B2: xf reads done (vu free for vh)

    // 3. round + store vh[pos][d] as f16x4 b64 (conflict-light)
#pragma unroll
    for (int n = 0; n < 4; ++n) {
      const int pos = n * 16 + c;
      const bool ok = (pos >= 1) && (pos <= 62) && (w0 - 1 + pos < LLEN);
      half4 hv;
#pragma unroll
      for (int r = 0; r < 4; ++r)
        hv[r] = ok ? (_Float16)vacc[n][r] : (_Float16)0.f;
      *(half4*)(vu + pos * QHP + wv * 16 + g * 4) = hv;
    }
    __syncthreads();   // B3: vh visible

    // 4. out GEMM: rows o (wv quarter), cols pos, contract d
    f32x4 oacc[4];
#pragma unroll
    for (int n = 0; n < 4; ++n)
#pragma unroll
      for (int r = 0; r < 4; ++r) oacc[n][r] = 0.f;
#pragma unroll
    for (int n = 0; n < 4; ++n) {
      const _Float16* vrow = vu + (n * 16 + c) * QHP + g * 8;
      const half8 b0 = *(const half8*)(vrow);
      const half8 b1 = *(const half8*)(vrow + 32);
      oacc[n] = MFMA16(aM[0], b0, oacc[n], 0, 0, 0);
      oacc[n] = MFMA16(aM[1], b1, oacc[n], 0, 0, 0);
    }
#pragma unroll
    for (int n = 0; n < 4; ++n) {
      const int pos = n * 16 + c;
      const int P = w0 - 1 + pos;
      if (pos >= 1 && pos <= 62 && P < LLEN) {
#pragma unroll
        for (int r = 0; r < 4; ++r)
          ob[(size_t)(wv * 16 + g * 4 + r) * LLEN + P] = oacc[n][r];
      }
    }
    __syncthreads();   // B4: vh reads done; drains stage vmcnt
  }
}

extern "C" void kernel_launch(void* const* d_in, const int* in_sizes, int n_in,
                              void* d_out, int out_size, void* d_ws, size_t ws_size,
                              hipStream_t stream) {
  (void)in_sizes; (void)n_in; (void)out_size; (void)ws_size;
  const float* x           = (const float*)d_in[0];
  const float* w_kv        = (const float*)d_in[1];
  const float* w_kv_dw     = (const float*)d_in[2];
  const float* w_q         = (const float*)d_in[3];
  const float* w_q_dw      = (const float*)d_in[4];
  const float* w_proj      = (const float*)d_in[5];
  const float* temperature = (const float*)d_in[6];
  float* out = (float*)d_out;

  float* G   = (float*)d_ws;            // 16384 f32
  float* nqp = G + 16384;               // 256
  float* nkp = nqp + 256;               // 256
  _Float16* Mh  = (_Float16*)(nkp + 256);  // 4*4096 halves
  _Float16* wqA = Mh + NB * 4096;       // 4096 halves each
  _Float16* wkA = wqA + 4096;
  _Float16* wvA = wkA + 4096;

  (void)hipMemsetAsync(G, 0, (size_t)(16384 + 512) * sizeof(float), stream);
  prep_kernel<<<dim3(16), dim3(256), 0, stream>>>(w_q, w_kv, wqA, wkA, wvA);
  qk_gram_kernel<<<dim3(BLKA, NB), dim3(256), 0, stream>>>(
      x, wqA, wkA, w_q_dw, w_kv_dw, G, nqp, nkp);
  attn_proj_kernel<<<dim3(NB), dim3(256), 0, stream>>>(
      G, nqp, nkp, w_proj, temperature, Mh);
  out_kernel<<<dim3(BLKC, NB), dim3(256), 0, stream>>>(
      x, wvA, w_kv_dw, Mh, out);
}